// Round 8
// baseline (438.494 us; speedup 1.0000x reference)
//
#include <hip/hip_runtime.h>
#include <hip/hip_bf16.h>
#include <math.h>

#define NNODES 50000
#define NEDGES 800000
#define EPTOT  (NEDGES + NNODES)   // 850000 edges incl self-loops
#define NEG_SLOPE 0.2f
#define BN_EPS 1e-5f
#define LOG2E 1.44269504088896f
#define ESLOT 64                   // fixed slots per node (max deg ~50 w.p. 1-1e-9)

// misc_prep block ranges: W1 prep | W2 prep | zero-fill (cnt + bnsums)
#define PB_W1  128                  // 2*128*128/256
#define PB_W2  (PB_W1 + 256)        // 2*256*128/256
#define PB_Z   50                   // 50*256*4 ints = 51200 >= NNODES
// gemm1 grid: x < GEMM1_GX -> gemm role; x >= GEMM1_GX -> edge-scatter role
#define GEMM1_GX 392
#define SCAT_NB  416               // per-y scatter blocks; 416*2*128*8 = 851968 >= EPTOT
#define SCAT_EPB 8                 // edges per thread (8-deep atomic MLP)

typedef __hip_bfloat16 bf16;
typedef __attribute__((ext_vector_type(8))) short short8;
typedef __attribute__((ext_vector_type(4))) float f32x4;
typedef __attribute__((ext_vector_type(2))) float f32x2;

__device__ __forceinline__ unsigned short f2us(float f){
    return (unsigned short)(__bfloat16_as_ushort(__float2bfloat16(f)));
}
// bf16 pair (one dword) -> two fp32 in 2 instructions
__device__ __forceinline__ f32x2 unpk(unsigned int w){
    union { unsigned int u; float f; } lo, hi;
    lo.u = w << 16; hi.u = w & 0xffff0000u;
    f32x2 r; r.x = lo.f; r.y = hi.f; return r;
}
__device__ __forceinline__ f32x2 pkmax(f32x2 a, f32x2 b){
#if __has_builtin(__builtin_elementwise_max)
    return __builtin_elementwise_max(a, b);
#else
    f32x2 r; r.x = fmaxf(a.x, b.x); r.y = fmaxf(a.y, b.y); return r;
#endif
}
__device__ __forceinline__ unsigned int pack2(float a, float b){
    return (unsigned int)f2us(a) | ((unsigned int)f2us(b) << 16);
}
__device__ __forceinline__ float softplusf(float x){
    return (x > 20.f) ? x : log1pf(__expf(x));
}

// v_add_f32 with DPP-permuted second operand: v + perm(v). Register-only.
template<int CTRL>
__device__ __forceinline__ float dppadd(float v){
    int p = __builtin_amdgcn_update_dpp(0, __float_as_int(v), CTRL, 0xf, 0xf, true);
    return v + __int_as_float(p);
}
// Sum across G contiguous lanes (group-aligned); result broadcast to all G lanes.
template<int G>
__device__ __forceinline__ float group_sum(float v){
    if constexpr (G == 16){
        v = dppadd<0x121>(v);   // row_ror:1
        v = dppadd<0x122>(v);   // row_ror:2
        v = dppadd<0x124>(v);   // row_ror:4
        v = dppadd<0x128>(v);   // row_ror:8
    } else {                    // G == 8
        v = dppadd<0xB1>(v);    // quad_perm [1,0,3,2] = xor1
        v = dppadd<0x4E>(v);    // quad_perm [2,3,0,1] = xor2
        v += __shfl_xor(v, 4, 64);
    }
    return v;
}

// ---- prep: weight transposes | zero-fill cnt+bnsums (replaces 2 memset dispatches) ----

__global__ __launch_bounds__(256) void misc_prep(
    const float* __restrict__ Wl1, const float* __restrict__ Wr1,
    const float* __restrict__ bl1, const float* __restrict__ br1,
    bf16* __restrict__ WT1, float* __restrict__ bc1,
    const float* __restrict__ Wl2, const float* __restrict__ Wr2,
    const float* __restrict__ bl2, const float* __restrict__ br2,
    bf16* __restrict__ WT2, float* __restrict__ bc2,
    int* __restrict__ cnt, float* __restrict__ bnsums)
{
    int b = blockIdx.x;
    if (b >= PB_W2){
        int zb = b - PB_W2;
        int i4 = (zb * 256 + threadIdx.x) * 4;
        if (i4 < NNODES){
            int4 z = {0, 0, 0, 0};
            *(int4*)(cnt + i4) = z;              // NNODES % 4 == 0
        }
        if (zb == 0)
            for (int i = threadIdx.x; i < 384; i += 256) bnsums[i] = 0.f;
        return;
    }
    if (b < PB_W1){
        int i = b * 256 + threadIdx.x;                  // 2*128*128
        int r = i >> 7, k = i & 127;
        const float* W = (r < 128) ? Wl1 : Wr1;
        int c = (r < 128) ? r : r - 128;
        WT1[i] = __float2bfloat16(W[k * 128 + c]);
        if (k == 0) bc1[r] = (r < 128) ? bl1[c] : br1[c];
    } else {
        int i = (b - PB_W1) * 256 + threadIdx.x;        // 2*256*128
        int r = i >> 7, k = i & 127;
        const float* W = (r < 256) ? Wl2 : Wr2;
        int c = (r < 256) ? r : r - 256;
        WT2[i] = __float2bfloat16(W[k * 256 + c]);
        if (k == 0) bc2[r] = (r < 256) ? bl2[c] : br2[c];
    }
}

// ---------------- MFMA GEMM: [M x 128] @ [128 x 2*DTOT] -> xl,xr [M x DTOT] bf16 ----------------
// A-fragments preloaded once per wave (register-cached), NT column tiles looped inside.
// grid.y * NT * 64 must equal 2*DTOT.
// AMODE: 1 = A fp32, converted in-register. 2 = A packed-bf16 (o1) with inline
// BN(sums,gamma,beta)+ReLU applied during fragment load.
// SCATTER: blocks with blockIdx.x >= GEMM1_GX run the edge scatter (R6-validated):
// 8 edges/thread, 8 independent atomicAdds (MLP over the RMW round-trip), guarded
// ushort stores. The device-atomic RMW pipe is the wall (~13 G/s, R6), but the
// work hides under gemm1's MFMA blocks and beats counting sort (R7: +21us).

template<int DTOT, int AMODE, int NT, bool SCATTER>
__global__ __launch_bounds__(128) void mfma_gemm(
    const void* __restrict__ A, const bf16* __restrict__ WT,
    const float* __restrict__ biascat,
    bf16* __restrict__ xl, bf16* __restrict__ xr,
    const float* __restrict__ bns, const float* __restrict__ gamma,
    const float* __restrict__ beta,
    const int* __restrict__ ei, int* __restrict__ cnt,
    unsigned short* __restrict__ esrc)
{
    if (SCATTER && blockIdx.x >= GEMM1_GX){
        int sid  = (blockIdx.x - GEMM1_GX) * 2 + blockIdx.y;
        int base = sid * (128 * SCAT_EPB) + threadIdx.x;
        int s[SCAT_EPB], d[SCAT_EPB], pos[SCAT_EPB];
        #pragma unroll
        for (int j = 0; j < SCAT_EPB; ++j){
            int e = base + j * 128;
            if (e < NEDGES){ s[j] = ei[e]; d[j] = ei[NEDGES + e]; }
            else if (e < EPTOT){ s[j] = d[j] = e - NEDGES; }
            else { s[j] = 0; d[j] = -1; }
        }
        #pragma unroll
        for (int j = 0; j < SCAT_EPB; ++j)
            pos[j] = (d[j] >= 0) ? atomicAdd(&cnt[d[j]], 1) : ESLOT;
        #pragma unroll
        for (int j = 0; j < SCAT_EPB; ++j)
            if (pos[j] < ESLOT) esrc[(d[j] << 6) + pos[j]] = (unsigned short)s[j];
        return;
    }

    int wave = threadIdx.x >> 6;
    int lane = threadIdx.x & 63;
    int quad = lane >> 4;
    int l16  = lane & 15;
    int m0 = blockIdx.x * 128 + wave * 64;
    const float* Af = (const float*)A;
    const unsigned int* Ao = (const unsigned int*)A;
    const short* Bp = (const short*)WT;

    short8 af[4][4];                     // [k-step][mt], 64 VGPRs
    #pragma unroll
    for (int k = 0; k < 4; ++k){
        float sc[8], sh[8];
        if (AMODE == 2){
            const float inv_n = 1.f / (float)NNODES;
            int cb = k * 32 + quad * 8;
            #pragma unroll
            for (int j = 0; j < 8; ++j){
                float mu = bns[cb + j] * inv_n;
                float s  = gamma[cb + j] * rsqrtf(bns[128 + cb + j] * inv_n - mu * mu + BN_EPS);
                sc[j] = s; sh[j] = beta[cb + j] - mu * s;
            }
        }
        #pragma unroll
        for (int mt = 0; mt < 4; ++mt){
            int m = m0 + mt * 16 + l16;
            m = (m < NNODES) ? m : (NNODES - 1);    // clamp; garbage rows never stored
            if (AMODE == 1){
                float4 v0 = *(const float4*)(Af + (size_t)m * 128 + k * 32 + quad * 8);
                float4 v1 = *(const float4*)(Af + (size_t)m * 128 + k * 32 + quad * 8 + 4);
                unsigned int* u = (unsigned int*)&af[k][mt];
                u[0] = pack2(v0.x, v0.y); u[1] = pack2(v0.z, v0.w);
                u[2] = pack2(v1.x, v1.y); u[3] = pack2(v1.z, v1.w);
            } else {
                // packed-bf16 A with inline BN + ReLU
                uint4 w = *(const uint4*)(Ao + (size_t)m * 64 + k * 16 + quad * 4);
                f32x2 v0 = unpk(w.x), v1 = unpk(w.y), v2 = unpk(w.z), v3 = unpk(w.w);
                float f0 = v0.x * sc[0] + sh[0], f1 = v0.y * sc[1] + sh[1];
                float f2 = v1.x * sc[2] + sh[2], f3 = v1.y * sc[3] + sh[3];
                float f4 = v2.x * sc[4] + sh[4], f5 = v2.y * sc[5] + sh[5];
                float f6 = v3.x * sc[6] + sh[6], f7 = v3.y * sc[7] + sh[7];
                f0 = f0 > 0.f ? f0 : 0.f; f1 = f1 > 0.f ? f1 : 0.f;
                f2 = f2 > 0.f ? f2 : 0.f; f3 = f3 > 0.f ? f3 : 0.f;
                f4 = f4 > 0.f ? f4 : 0.f; f5 = f5 > 0.f ? f5 : 0.f;
                f6 = f6 > 0.f ? f6 : 0.f; f7 = f7 > 0.f ? f7 : 0.f;
                unsigned int* u = (unsigned int*)&af[k][mt];
                u[0] = pack2(f0, f1); u[1] = pack2(f2, f3);
                u[2] = pack2(f4, f5); u[3] = pack2(f6, f7);
            }
        }
    }

    for (int t = 0; t < NT; ++t){
        int n0 = (blockIdx.y * NT + t) * 64;
        f32x4 acc[4][4] = {};
        #pragma unroll
        for (int k = 0; k < 4; ++k){
            short8 bfr[4];
            #pragma unroll
            for (int nt = 0; nt < 4; ++nt){
                int n = n0 + nt * 16 + l16;
                bfr[nt] = *(const short8*)(Bp + (size_t)n * 128 + k * 32 + quad * 8);
            }
            #pragma unroll
            for (int mt = 0; mt < 4; ++mt)
                #pragma unroll
                for (int nt = 0; nt < 4; ++nt)
                    acc[mt][nt] = __builtin_amdgcn_mfma_f32_16x16x32_bf16(af[k][mt], bfr[nt], acc[mt][nt], 0, 0, 0);
        }
        #pragma unroll
        for (int nt = 0; nt < 4; ++nt){
            int n = n0 + nt * 16 + l16;
            float bi = biascat[n];
            bf16* outp = (n < DTOT) ? xl : xr;
            int c = (n < DTOT) ? n : n - DTOT;
            #pragma unroll
            for (int mt = 0; mt < 4; ++mt)
                #pragma unroll
                for (int r = 0; r < 4; ++r){
                    int m = m0 + mt * 16 + quad * 4 + r;
                    if (m < NNODES)
                        outp[(size_t)m * DTOT + c] = __float2bfloat16(acc[mt][nt][r] + bi);
                }
        }
    }
}

// ---------------- GATv2 aggregation (wave/node + software-pipelined gathers) ----------------
// Block = 256 threads = 4 waves = 4 INDEPENDENT nodes (no barrier, no LDS).
// Wave lane layout: el = lane/LPE (edge within gather), h = head, cl = channel chunk.
// Gathers software-pipelined one full iteration ahead (4 loads in flight, R5 win).
// esrc is ushort (zero-extended on load; clamped shuffles never consume garbage).
// Dual-chain + DPP group reduce + pkmax leaky + exp2 domain (all prior-validated).
// !MEAN: packed-bf16 rows.
// MEAN (conv2): head-mean + bias2 in registers; cols 0..63 -> o2n (N x 64 fp32,
// BN2 stats follow), cols 64..127 -> softplus DIRECTLY to out (needs no BN stats
// -> removes half of final_out and half of o2 traffic).

template<int C, bool MEAN>
__global__ __launch_bounds__(256) void gat_aggregate(
    const bf16* __restrict__ xl, const bf16* __restrict__ xr,
    const float* __restrict__ att, const int* __restrict__ cnt,
    const unsigned short* __restrict__ esrc, void* __restrict__ outv,
    const float* __restrict__ bias2, float* __restrict__ outsp)
{
    constexpr int GH  = C / 8;        // lanes per head-chunk: 8 (C=64) / 16 (C=128)
    constexpr int LPE = 2 * GH;       // lanes per edge (both heads): 16 / 32
    constexpr int EL  = 64 / LPE;     // edges per gather: 4 / 2
    constexpr int RB  = 4 * C;        // xl/xr row bytes: 256 / 512
    int lane = threadIdx.x & 63;
    int wave = threadIdx.x >> 6;
    int n    = blockIdx.x * 4 + wave;           // 50000 % 4 == 0: always valid
    int el   = lane / LPE;
    int h    = (lane / GH) & 1;
    int cl   = lane % GH;
    int rowoff = h * (C * 2) + cl * 16;         // byte offset within a row
    const char* xlp = (const char*)xl;

    // independent loads up front: bucket sources, count, xr slice, att slice
    int srcAll = (int)esrc[(n << 6) + lane];    // whole bucket, 1 coalesced 128B load
    int cc = cnt[n];
    int c = (cc < ESLOT) ? cc : ESLOT;          // >=1 (self-loop)
    uint4 xw = *(const uint4*)((const char*)xr + (unsigned)n * RB + rowoff);
    f32x2 xr0 = unpk(xw.x), xr1 = unpk(xw.y), xr2v = unpk(xw.z), xr3 = unpk(xw.w);
    const float* ap = att + h * C + cl * 8;
    f32x2 av0 = {ap[0] * LOG2E, ap[1] * LOG2E};
    f32x2 av1 = {ap[2] * LOG2E, ap[3] * LOG2E};
    f32x2 av2 = {ap[4] * LOG2E, ap[5] * LOG2E};
    f32x2 av3 = {ap[6] * LOG2E, ap[7] * LOG2E};
    float b2r[8];
    if (MEAN){
        #pragma unroll
        for (int v = 0; v < 8; ++v) b2r[v] = bias2[cl * 8 + v];
    }

    float den = 0.f;
    f32x2 a0 = {0.f,0.f}, a1 = {0.f,0.f}, a2 = {0.f,0.f}, a3 = {0.f,0.f};

    // prologue: issue iteration-0 gathers
    int i0 = el, i1 = EL + el;
    int sa = __shfl(srcAll, (i0 < c) ? i0 : (c - 1), 64);
    int sb = __shfl(srcAll, (i1 < c) ? i1 : (c - 1), 64);
    uint4 wa = *(const uint4*)(xlp + ((unsigned)sa * (unsigned)RB + rowoff));
    uint4 wb = *(const uint4*)(xlp + ((unsigned)sb * (unsigned)RB + rowoff));

    int p = 0;
    for (; p + EL < c; p += 2 * EL){            // chain A fully live (wave-uniform)
        float mkb = (p + EL + el < c) ? 0.f : -1e30f;
        int pn = p + 2 * EL;
        uint4 wa_n, wb_n;
        bool pf = pn < c;                       // wave-uniform prefetch guard
        if (pf){                                // issue NEXT gathers before math
            int ian = pn + el, ibn = pn + EL + el;
            int sa_n = __shfl(srcAll, (ian < c) ? ian : (c - 1), 64);
            int sb_n = __shfl(srcAll, (ibn < c) ? ibn : (c - 1), 64);
            wa_n = *(const uint4*)(xlp + ((unsigned)sa_n * (unsigned)RB + rowoff));
            wb_n = *(const uint4*)(xlp + ((unsigned)sb_n * (unsigned)RB + rowoff));
        }

        f32x2 xa0 = unpk(wa.x), xa1 = unpk(wa.y), xa2 = unpk(wa.z), xa3 = unpk(wa.w);
        f32x2 xb0 = unpk(wb.x), xb1 = unpk(wb.y), xb2 = unpk(wb.z), xb3 = unpk(wb.w);

        f32x2 ua0 = xa0 + xr0, ua1 = xa1 + xr1, ua2 = xa2 + xr2v, ua3 = xa3 + xr3;
        f32x2 ub0 = xb0 + xr0, ub1 = xb1 + xr1, ub2 = xb2 + xr2v, ub3 = xb3 + xr3;

        f32x2 ppa = pkmax(ua0, ua0 * NEG_SLOPE) * av0;
        ppa += pkmax(ua1, ua1 * NEG_SLOPE) * av1;
        ppa += pkmax(ua2, ua2 * NEG_SLOPE) * av2;
        ppa += pkmax(ua3, ua3 * NEG_SLOPE) * av3;
        f32x2 ppb = pkmax(ub0, ub0 * NEG_SLOPE) * av0;
        ppb += pkmax(ub1, ub1 * NEG_SLOPE) * av1;
        ppb += pkmax(ub2, ub2 * NEG_SLOPE) * av2;
        ppb += pkmax(ub3, ub3 * NEG_SLOPE) * av3;
        float parta = group_sum<GH>(ppa.x + ppa.y);   // DPP, register-only
        float partb = group_sum<GH>(ppb.x + ppb.y);
        float exa = exp2f(parta);
        float exb = exp2f(partb + mkb);
        den += exa + exb;
        f32x2 ea = {exa, exa}, eb = {exb, exb};
        a0 += ea * xa0; a1 += ea * xa1; a2 += ea * xa2; a3 += ea * xa3;
        a0 += eb * xb0; a1 += eb * xb1; a2 += eb * xb2; a3 += eb * xb3;
        if (pf){ wa = wa_n; wb = wb_n; }
    }
    if (p < c){                                 // tail: <=EL edges, single chain
        // wa holds the prefetched gather for slot p+el (prologue or last loop iter)
        float mka = (p + el < c) ? 0.f : -1e30f;
        f32x2 xa0 = unpk(wa.x), xa1 = unpk(wa.y), xa2 = unpk(wa.z), xa3 = unpk(wa.w);
        f32x2 ua0 = xa0 + xr0, ua1 = xa1 + xr1, ua2 = xa2 + xr2v, ua3 = xa3 + xr3;

        f32x2 ppa = pkmax(ua0, ua0 * NEG_SLOPE) * av0;
        ppa += pkmax(ua1, ua1 * NEG_SLOPE) * av1;
        ppa += pkmax(ua2, ua2 * NEG_SLOPE) * av2;
        ppa += pkmax(ua3, ua3 * NEG_SLOPE) * av3;
        float parta = group_sum<GH>(ppa.x + ppa.y);
        float exa = exp2f(parta + mka);         // 0 for dead slots
        den += exa;
        f32x2 ea = {exa, exa};
        a0 += ea * xa0; a1 += ea * xa1; a2 += ea * xa2; a3 += ea * xa3;
    }

    // merge the EL edge-group partials (cold path: once per node)
    #pragma unroll
    for (int mask = LPE; mask < 64; mask <<= 1){
        den  += __shfl_xor(den, mask, 64);
        a0.x += __shfl_xor(a0.x, mask, 64); a0.y += __shfl_xor(a0.y, mask, 64);
        a1.x += __shfl_xor(a1.x, mask, 64); a1.y += __shfl_xor(a1.y, mask, 64);
        a2.x += __shfl_xor(a2.x, mask, 64); a2.y += __shfl_xor(a2.y, mask, 64);
        a3.x += __shfl_xor(a3.x, mask, 64); a3.y += __shfl_xor(a3.y, mask, 64);
    }
    float inv = 1.f / den;

    if (!MEAN){
        if (el == 0){
            uint4 o;
            o.x = pack2(a0.x * inv, a0.y * inv);
            o.y = pack2(a1.x * inv, a1.y * inv);
            o.z = pack2(a2.x * inv, a2.y * inv);
            o.w = pack2(a3.x * inv, a3.y * inv);
            *(uint4*)((char*)outv + (size_t)n * RB + rowoff) = o;
        }
    } else {
        // per-lane normalized values, then head-mean via shfl_xor(16) (h-bit)
        float v0 = a0.x * inv, v1 = a0.y * inv, v2 = a1.x * inv, v3 = a1.y * inv;
        float v4 = a2.x * inv, v5 = a2.y * inv, v6 = a3.x * inv, v7 = a3.y * inv;
        v0 = 0.5f * (v0 + __shfl_xor(v0, 16, 64)) + b2r[0];
        v1 = 0.5f * (v1 + __shfl_xor(v1, 16, 64)) + b2r[1];
        v2 = 0.5f * (v2 + __shfl_xor(v2, 16, 64)) + b2r[2];
        v3 = 0.5f * (v3 + __shfl_xor(v3, 16, 64)) + b2r[3];
        v4 = 0.5f * (v4 + __shfl_xor(v4, 16, 64)) + b2r[4];
        v5 = 0.5f * (v5 + __shfl_xor(v5, 16, 64)) + b2r[5];
        v6 = 0.5f * (v6 + __shfl_xor(v6, 16, 64)) + b2r[6];
        v7 = 0.5f * (v7 + __shfl_xor(v7, 16, 64)) + b2r[7];
        if (el == 0 && h == 0){
            if (cl < 8){
                // cols 0..63: BN2 follows -> o2n workspace (N x 64 fp32)
                float* outp = (float*)outv + (size_t)n * 64 + cl * 8;
                float4 w0 = {v0, v1, v2, v3};
                float4 w1 = {v4, v5, v6, v7};
                *(float4*)(outp) = w0;
                *(float4*)(outp + 4) = w1;
            } else {
                // cols 64..127: softplus needs no BN stats -> straight to out
                float* outp = outsp + (size_t)n * 128 + cl * 8;   // cl*8 in [64,120]
                float4 w0 = {softplusf(v0), softplusf(v1), softplusf(v2), softplusf(v3)};
                float4 w1 = {softplusf(v4), softplusf(v5), softplusf(v6), softplusf(v7)};
                *(float4*)(outp) = w0;
                *(float4*)(outp + 4) = w1;
            }
        }
    }
}

// ---------------- BatchNorm ----------------

// stats over packed-bf16 matrix [N][128]
__global__ void bn_stats_bf16(const unsigned int* __restrict__ x, float* __restrict__ sums){
    __shared__ float ls[1024];
    int t = threadIdx.x;              // 256 threads
    int c2 = t & 63;                  // dword column (covers ch 2*c2, 2*c2+1)
    int rg = t >> 6;                  // 4 row groups
    float s0 = 0.f, q0 = 0.f, s1 = 0.f, q1 = 0.f;
    for (int r = blockIdx.x * 4 + rg; r < NNODES; r += gridDim.x * 4){
        f32x2 v = unpk(x[(size_t)r * 64 + c2]);
        s0 += v.x; q0 += v.x * v.x;
        s1 += v.y; q1 += v.y * v.y;
    }
    ls[t] = s0; ls[256 + t] = q0; ls[512 + t] = s1; ls[768 + t] = q1;
    __syncthreads();
    if (rg == 0){
        for (int g = 1; g < 4; ++g){
            s0 += ls[g * 64 + c2];       q0 += ls[256 + g * 64 + c2];
            s1 += ls[512 + g * 64 + c2]; q1 += ls[768 + g * 64 + c2];
        }
        atomicAdd(&sums[2 * c2], s0);
        atomicAdd(&sums[128 + 2 * c2], q0);
        atomicAdd(&sums[2 * c2 + 1], s1);
        atomicAdd(&sums[128 + 2 * c2 + 1], q1);
    }
}

// stats over o2n [N][64] fp32 (dense, stride 64)
__global__ void bn_stats_o2(const float* __restrict__ x, float* __restrict__ sums){
    __shared__ float ls[512];
    int t = threadIdx.x;              // 256 threads
    int col = t & 63;
    int rg  = t >> 6;                 // 4 row groups
    float s = 0.f, q = 0.f;
    for (int r = blockIdx.x * 4 + rg; r < NNODES; r += gridDim.x * 4){
        float v = x[(size_t)r * 64 + col];
        s += v; q += v * v;
    }
    ls[t] = s; ls[256 + t] = q;
    __syncthreads();
    if (rg == 0){
        for (int g = 1; g < 4; ++g){ s += ls[g * 64 + col]; q += ls[256 + g * 64 + col]; }
        atomicAdd(&sums[col], s);
        atomicAdd(&sums[64 + col], q);
    }
}

// o2n -> out cols 0..63 only: BN (affine=False). Softplus half already written by agg2.
__global__ void final_out(const float* __restrict__ o2n, const float* __restrict__ sums,
                          float* __restrict__ out){
    int i = blockIdx.x * blockDim.x + threadIdx.x;
    if (i >= NNODES * 16) return;
    int n  = i >> 4;
    int c4 = (i & 15) * 4;
    float4 v = *(const float4*)(o2n + (size_t)n * 64 + c4);
    const float* vp = (const float*)&v;
    float4 r;
    float* rp = (float*)&r;
    const float inv_n = 1.f / (float)NNODES;
    #pragma unroll
    for (int k = 0; k < 4; ++k){
        float mu = sums[c4 + k] * inv_n;
        float rsig = rsqrtf(sums[64 + c4 + k] * inv_n - mu * mu + BN_EPS);
        rp[k] = (vp[k] - mu) * rsig;
    }
    *(float4*)(out + (size_t)n * 128 + c4) = r;
}

// ---------------- launch ----------------

extern "C" void kernel_launch(void* const* d_in, const int* in_sizes, int n_in,
                              void* d_out, int out_size, void* d_ws, size_t ws_size,
                              hipStream_t stream) {
    const float* x     = (const float*)d_in[0];
    const int*   ei    = (const int*)d_in[1];
    const float* W_l1  = (const float*)d_in[2];
    const float* b_l1  = (const float*)d_in[3];
    const float* W_r1  = (const float*)d_in[4];
    const float* b_r1  = (const float*)d_in[5];
    const float* att1  = (const float*)d_in[6];
    // d_in[7] = bias1: cancels through BN1 (constant per-column shift) -> unused
    const float* gamma1 = (const float*)d_in[8];
    const float* beta1  = (const float*)d_in[9];
    const float* W_l2  = (const float*)d_in[10];
    const float* b_l2  = (const float*)d_in[11];
    const float* W_r2  = (const float*)d_in[12];
    const float* b_r2  = (const float*)d_in[13];
    const float* att2  = (const float*)d_in[14];
    const float* bias2 = (const float*)d_in[15];
    float* out = (float*)d_out;

    char* w = (char*)d_ws;
    size_t off = 0;
    auto alloc = [&](size_t bytes) -> void* {
        void* p = w + off;
        off += (bytes + 255) & ~(size_t)255;
        return p;
    };
    const size_t NF  = (size_t)NNODES * 128 * 4;   // 25.6 MB fp32
    bf16*  xl1   = (bf16*) alloc(NF / 2);          // N x 128 bf16
    bf16*  xr1   = (bf16*) alloc(NF / 2);
    bf16*  xl2   = (bf16*) alloc(NF);              // N x 256 bf16
    bf16*  xr2   = (bf16*) alloc(NF);
    unsigned int* o1 = (unsigned int*)alloc(NF / 2);  // N x 128 bf16 (packed)
    float* o2n   = (float*)alloc(NF / 2);          // N x 64 fp32 (BN half only)
    bf16*  WT1   = (bf16*) alloc(256 * 128 * 2);
    bf16*  WT2   = (bf16*) alloc(512 * 128 * 2);
    float* bc1   = (float*)alloc(256 * 4);
    float* bc2   = (float*)alloc(512 * 4);
    int*   cnt    = (int*)  alloc((size_t)NNODES * 4);
    unsigned short* esrc = (unsigned short*)alloc((size_t)NNODES * ESLOT * 2); // 6.4 MB
    float* bnsums = (float*)alloc(384 * 4);   // bn1: 256 (sum|sq), bn2: 128 (sum|sq)
    float* bn1s = bnsums;
    float* bn2s = bnsums + 256;

    // weight transposes + cnt/bnsums zero-fill (replaces 2 memset dispatches)
    misc_prep<<<PB_W2 + PB_Z, 256, 0, stream>>>(W_l1, W_r1, b_l1, b_r1, WT1, bc1,
                                                W_l2, W_r2, b_l2, b_r2, WT2, bc2,
                                                cnt, bnsums);

    // conv1 gemm (A = fp32 x) + edge scatter hidden in extra blocks
    mfma_gemm<128, 1, 2, true><<<dim3(GEMM1_GX + SCAT_NB, 2), 128, 0, stream>>>(
        x, WT1, bc1, xl1, xr1, nullptr, nullptr, nullptr, ei, cnt, esrc);
    gat_aggregate<64, false><<<NNODES / 4, 256, 0, stream>>>(
        xl1, xr1, att1, cnt, esrc, o1, bias2, nullptr);

    // bn1 stats; BN+ReLU applied inline in gemm2's A-fragment loader
    bn_stats_bf16<<<512, 256, 0, stream>>>(o1, bn1s);

    // conv2 -> xl2/xr2; A = o1 with inline BN1+ReLU
    mfma_gemm<256, 2, 2, false><<<dim3(392, 4), 128, 0, stream>>>(
        o1, WT2, bc2, xl2, xr2, bn1s, gamma1, beta1, nullptr, nullptr, nullptr);
    // agg2: BN half -> o2n, softplus half -> out directly
    gat_aggregate<128, true><<<NNODES / 4, 256, 0, stream>>>(
        xl2, xr2, att2, cnt, esrc, o2n, bias2, out);

    // bn2 stats on o2n, then BN -> out cols 0..63
    bn_stats_o2<<<512, 256, 0, stream>>>(o2n, bn2s);
    final_out<<<(NNODES * 16 + 255) / 256, 256, 0, stream>>>(o2n, bn2s, out);
}

// Round 9
// 378.912 us; speedup vs baseline: 1.1572x; 1.1572x over previous
//
#include <hip/hip_runtime.h>
#include <hip/hip_bf16.h>
#include <math.h>

#define NNODES 50000
#define NEDGES 800000
#define EPTOT  (NEDGES + NNODES)   // 850000 edges incl self-loops
#define NEG_SLOPE 0.2f
#define BN_EPS 1e-5f
#define LOG2E 1.44269504088896f
#define ESLOT 64                   // fixed slots per node (max deg ~50 w.p. 1-1e-9)

// misc_prep block ranges: W1 prep | W2 prep | zero-fill (cnt + bnsums)
#define PB_W1  128                  // 2*128*128/256
#define PB_W2  (PB_W1 + 256)        // 2*256*128/256
#define PB_Z   50                   // 50*256*4 ints = 51200 >= NNODES
// gemm1 grid: x < GEMM1_GX -> gemm role; x >= GEMM1_GX -> edge-scatter role
#define GEMM1_GX 392
#define SCAT_NB  416               // per-y scatter blocks; 416*2*128*8 = 851968 >= EPTOT
#define SCAT_EPB 8                 // edges per thread (8-deep atomic MLP)

typedef __hip_bfloat16 bf16;
typedef __attribute__((ext_vector_type(8))) short short8;
typedef __attribute__((ext_vector_type(4))) float f32x4;
typedef __attribute__((ext_vector_type(2))) float f32x2;

__device__ __forceinline__ unsigned short f2us(float f){
    return (unsigned short)(__bfloat16_as_ushort(__float2bfloat16(f)));
}
// bf16 pair (one dword) -> two fp32 in 2 instructions
__device__ __forceinline__ f32x2 unpk(unsigned int w){
    union { unsigned int u; float f; } lo, hi;
    lo.u = w << 16; hi.u = w & 0xffff0000u;
    f32x2 r; r.x = lo.f; r.y = hi.f; return r;
}
__device__ __forceinline__ f32x2 pkmax(f32x2 a, f32x2 b){
#if __has_builtin(__builtin_elementwise_max)
    return __builtin_elementwise_max(a, b);
#else
    f32x2 r; r.x = fmaxf(a.x, b.x); r.y = fmaxf(a.y, b.y); return r;
#endif
}
__device__ __forceinline__ unsigned int pack2(float a, float b){
    return (unsigned int)f2us(a) | ((unsigned int)f2us(b) << 16);
}

// v_add_f32 with DPP-permuted second operand: v + perm(v). Register-only.
template<int CTRL>
__device__ __forceinline__ float dppadd(float v){
    int p = __builtin_amdgcn_update_dpp(0, __float_as_int(v), CTRL, 0xf, 0xf, true);
    return v + __int_as_float(p);
}
// Sum across G contiguous lanes (group-aligned); result broadcast to all G lanes.
template<int G>
__device__ __forceinline__ float group_sum(float v){
    if constexpr (G == 16){
        v = dppadd<0x121>(v);   // row_ror:1
        v = dppadd<0x122>(v);   // row_ror:2
        v = dppadd<0x124>(v);   // row_ror:4
        v = dppadd<0x128>(v);   // row_ror:8
    } else {                    // G == 8
        v = dppadd<0xB1>(v);    // quad_perm [1,0,3,2] = xor1
        v = dppadd<0x4E>(v);    // quad_perm [2,3,0,1] = xor2
        v += __shfl_xor(v, 4, 64);
    }
    return v;
}

// ---- prep: weight transposes | zero-fill cnt+bnsums (replaces 2 memset dispatches) ----

__global__ __launch_bounds__(256) void misc_prep(
    const float* __restrict__ Wl1, const float* __restrict__ Wr1,
    const float* __restrict__ bl1, const float* __restrict__ br1,
    bf16* __restrict__ WT1, float* __restrict__ bc1,
    const float* __restrict__ Wl2, const float* __restrict__ Wr2,
    const float* __restrict__ bl2, const float* __restrict__ br2,
    bf16* __restrict__ WT2, float* __restrict__ bc2,
    int* __restrict__ cnt, float* __restrict__ bnsums)
{
    int b = blockIdx.x;
    if (b >= PB_W2){
        int zb = b - PB_W2;
        int i4 = (zb * 256 + threadIdx.x) * 4;
        if (i4 < NNODES){
            int4 z = {0, 0, 0, 0};
            *(int4*)(cnt + i4) = z;              // NNODES % 4 == 0
        }
        if (zb == 0)
            for (int i = threadIdx.x; i < 384; i += 256) bnsums[i] = 0.f;
        return;
    }
    if (b < PB_W1){
        int i = b * 256 + threadIdx.x;                  // 2*128*128
        int r = i >> 7, k = i & 127;
        const float* W = (r < 128) ? Wl1 : Wr1;
        int c = (r < 128) ? r : r - 128;
        WT1[i] = __float2bfloat16(W[k * 128 + c]);
        if (k == 0) bc1[r] = (r < 128) ? bl1[c] : br1[c];
    } else {
        int i = (b - PB_W1) * 256 + threadIdx.x;        // 2*256*128
        int r = i >> 7, k = i & 127;
        const float* W = (r < 256) ? Wl2 : Wr2;
        int c = (r < 256) ? r : r - 256;
        WT2[i] = __float2bfloat16(W[k * 256 + c]);
        if (k == 0) bc2[r] = (r < 256) ? bl2[c] : br2[c];
    }
}

// ---------------- MFMA GEMM: [M x 128] @ [128 x 2*DTOT] -> xl,xr [M x DTOT] bf16 ----------------
// A-fragments preloaded once per wave (register-cached), NT column tiles looped inside.
// grid.y * NT * 64 must equal 2*DTOT.
// AMODE: 1 = A fp32, converted in-register. 2 = A packed-bf16 (o1) with inline
// BN(sums,gamma,beta)+ReLU applied during fragment load.
// SCATTER: blocks with blockIdx.x >= GEMM1_GX run the edge scatter (R6-validated):
// 8 edges/thread, 8 independent atomicAdds (MLP over the RMW round-trip), guarded
// ushort stores. Device-atomic RMW pipe is the wall (~13 G/s, R6) but the work
// hides under gemm1's MFMA blocks; beats counting sort (R7: +21us).

template<int DTOT, int AMODE, int NT, bool SCATTER>
__global__ __launch_bounds__(128) void mfma_gemm(
    const void* __restrict__ A, const bf16* __restrict__ WT,
    const float* __restrict__ biascat,
    bf16* __restrict__ xl, bf16* __restrict__ xr,
    const float* __restrict__ bns, const float* __restrict__ gamma,
    const float* __restrict__ beta,
    const int* __restrict__ ei, int* __restrict__ cnt,
    unsigned short* __restrict__ esrc)
{
    if (SCATTER && blockIdx.x >= GEMM1_GX){
        int sid  = (blockIdx.x - GEMM1_GX) * 2 + blockIdx.y;
        int base = sid * (128 * SCAT_EPB) + threadIdx.x;
        int s[SCAT_EPB], d[SCAT_EPB], pos[SCAT_EPB];
        #pragma unroll
        for (int j = 0; j < SCAT_EPB; ++j){
            int e = base + j * 128;
            if (e < NEDGES){ s[j] = ei[e]; d[j] = ei[NEDGES + e]; }
            else if (e < EPTOT){ s[j] = d[j] = e - NEDGES; }
            else { s[j] = 0; d[j] = -1; }
        }
        #pragma unroll
        for (int j = 0; j < SCAT_EPB; ++j)
            pos[j] = (d[j] >= 0) ? atomicAdd(&cnt[d[j]], 1) : ESLOT;
        #pragma unroll
        for (int j = 0; j < SCAT_EPB; ++j)
            if (pos[j] < ESLOT) esrc[(d[j] << 6) + pos[j]] = (unsigned short)s[j];
        return;
    }

    int wave = threadIdx.x >> 6;
    int lane = threadIdx.x & 63;
    int quad = lane >> 4;
    int l16  = lane & 15;
    int m0 = blockIdx.x * 128 + wave * 64;
    const float* Af = (const float*)A;
    const unsigned int* Ao = (const unsigned int*)A;
    const short* Bp = (const short*)WT;

    short8 af[4][4];                     // [k-step][mt], 64 VGPRs
    #pragma unroll
    for (int k = 0; k < 4; ++k){
        float sc[8], sh[8];
        if (AMODE == 2){
            const float inv_n = 1.f / (float)NNODES;
            int cb = k * 32 + quad * 8;
            #pragma unroll
            for (int j = 0; j < 8; ++j){
                float mu = bns[cb + j] * inv_n;
                float s  = gamma[cb + j] * rsqrtf(bns[128 + cb + j] * inv_n - mu * mu + BN_EPS);
                sc[j] = s; sh[j] = beta[cb + j] - mu * s;
            }
        }
        #pragma unroll
        for (int mt = 0; mt < 4; ++mt){
            int m = m0 + mt * 16 + l16;
            m = (m < NNODES) ? m : (NNODES - 1);    // clamp; garbage rows never stored
            if (AMODE == 1){
                float4 v0 = *(const float4*)(Af + (size_t)m * 128 + k * 32 + quad * 8);
                float4 v1 = *(const float4*)(Af + (size_t)m * 128 + k * 32 + quad * 8 + 4);
                unsigned int* u = (unsigned int*)&af[k][mt];
                u[0] = pack2(v0.x, v0.y); u[1] = pack2(v0.z, v0.w);
                u[2] = pack2(v1.x, v1.y); u[3] = pack2(v1.z, v1.w);
            } else {
                // packed-bf16 A with inline BN + ReLU
                uint4 w = *(const uint4*)(Ao + (size_t)m * 64 + k * 16 + quad * 4);
                f32x2 v0 = unpk(w.x), v1 = unpk(w.y), v2 = unpk(w.z), v3 = unpk(w.w);
                float f0 = v0.x * sc[0] + sh[0], f1 = v0.y * sc[1] + sh[1];
                float f2 = v1.x * sc[2] + sh[2], f3 = v1.y * sc[3] + sh[3];
                float f4 = v2.x * sc[4] + sh[4], f5 = v2.y * sc[5] + sh[5];
                float f6 = v3.x * sc[6] + sh[6], f7 = v3.y * sc[7] + sh[7];
                f0 = f0 > 0.f ? f0 : 0.f; f1 = f1 > 0.f ? f1 : 0.f;
                f2 = f2 > 0.f ? f2 : 0.f; f3 = f3 > 0.f ? f3 : 0.f;
                f4 = f4 > 0.f ? f4 : 0.f; f5 = f5 > 0.f ? f5 : 0.f;
                f6 = f6 > 0.f ? f6 : 0.f; f7 = f7 > 0.f ? f7 : 0.f;
                unsigned int* u = (unsigned int*)&af[k][mt];
                u[0] = pack2(f0, f1); u[1] = pack2(f2, f3);
                u[2] = pack2(f4, f5); u[3] = pack2(f6, f7);
            }
        }
    }

    for (int t = 0; t < NT; ++t){
        int n0 = (blockIdx.y * NT + t) * 64;
        f32x4 acc[4][4] = {};
        #pragma unroll
        for (int k = 0; k < 4; ++k){
            short8 bfr[4];
            #pragma unroll
            for (int nt = 0; nt < 4; ++nt){
                int n = n0 + nt * 16 + l16;
                bfr[nt] = *(const short8*)(Bp + (size_t)n * 128 + k * 32 + quad * 8);
            }
            #pragma unroll
            for (int mt = 0; mt < 4; ++mt)
                #pragma unroll
                for (int nt = 0; nt < 4; ++nt)
                    acc[mt][nt] = __builtin_amdgcn_mfma_f32_16x16x32_bf16(af[k][mt], bfr[nt], acc[mt][nt], 0, 0, 0);
        }
        #pragma unroll
        for (int nt = 0; nt < 4; ++nt){
            int n = n0 + nt * 16 + l16;
            float bi = biascat[n];
            bf16* outp = (n < DTOT) ? xl : xr;
            int c = (n < DTOT) ? n : n - DTOT;
            #pragma unroll
            for (int mt = 0; mt < 4; ++mt)
                #pragma unroll
                for (int r = 0; r < 4; ++r){
                    int m = m0 + mt * 16 + quad * 4 + r;
                    if (m < NNODES)
                        outp[(size_t)m * DTOT + c] = __float2bfloat16(acc[mt][nt][r] + bi);
                }
        }
    }
}

// ---------------- GATv2 aggregation (wave/node + software-pipelined gathers) ----------------
// Block = 256 threads = 4 waves = 4 INDEPENDENT nodes (no barrier, no LDS).
// Wave lane layout: el = lane/LPE (edge within gather), h = head, cl = channel chunk.
// Gathers software-pipelined one full iteration ahead (4 loads in flight, R5 win).
// esrc is ushort (zero-extended on load; clamped shuffles never consume garbage).
// Dual-chain + DPP group reduce + pkmax leaky + exp2 domain (all prior-validated).
// !MEAN: packed-bf16 rows. MEAN: 0.5*(h0+h1)+bias2 -> fp32 rows.
// NOTE (R8 lesson): do NOT split the MEAN epilogue by column class / add softplus
// here — that source change perturbed main-loop codegen (65 -> 142us, VALUBusy 95%).

template<int C, bool MEAN>
__global__ __launch_bounds__(256) void gat_aggregate(
    const bf16* __restrict__ xl, const bf16* __restrict__ xr,
    const float* __restrict__ att, const int* __restrict__ cnt,
    const unsigned short* __restrict__ esrc, void* __restrict__ outv,
    const float* __restrict__ bias2)
{
    constexpr int GH  = C / 8;        // lanes per head-chunk: 8 (C=64) / 16 (C=128)
    constexpr int LPE = 2 * GH;       // lanes per edge (both heads): 16 / 32
    constexpr int EL  = 64 / LPE;     // edges per gather: 4 / 2
    constexpr int RB  = 4 * C;        // xl/xr row bytes: 256 / 512
    int lane = threadIdx.x & 63;
    int wave = threadIdx.x >> 6;
    int n    = blockIdx.x * 4 + wave;           // 50000 % 4 == 0: always valid
    int el   = lane / LPE;
    int h    = (lane / GH) & 1;
    int cl   = lane % GH;
    int rowoff = h * (C * 2) + cl * 16;         // byte offset within a row
    const char* xlp = (const char*)xl;

    // independent loads up front: bucket sources, count, xr slice, att slice
    int srcAll = (int)esrc[(n << 6) + lane];    // whole bucket, 1 coalesced 128B load
    int cc = cnt[n];
    int c = (cc < ESLOT) ? cc : ESLOT;          // >=1 (self-loop)
    uint4 xw = *(const uint4*)((const char*)xr + (unsigned)n * RB + rowoff);
    f32x2 xr0 = unpk(xw.x), xr1 = unpk(xw.y), xr2v = unpk(xw.z), xr3 = unpk(xw.w);
    const float* ap = att + h * C + cl * 8;
    f32x2 av0 = {ap[0] * LOG2E, ap[1] * LOG2E};
    f32x2 av1 = {ap[2] * LOG2E, ap[3] * LOG2E};
    f32x2 av2 = {ap[4] * LOG2E, ap[5] * LOG2E};
    f32x2 av3 = {ap[6] * LOG2E, ap[7] * LOG2E};
    float b2r[8];
    if (MEAN){
        #pragma unroll
        for (int v = 0; v < 8; ++v) b2r[v] = bias2[cl * 8 + v];
    }

    float den = 0.f;
    f32x2 a0 = {0.f,0.f}, a1 = {0.f,0.f}, a2 = {0.f,0.f}, a3 = {0.f,0.f};

    // prologue: issue iteration-0 gathers
    int i0 = el, i1 = EL + el;
    int sa = __shfl(srcAll, (i0 < c) ? i0 : (c - 1), 64);
    int sb = __shfl(srcAll, (i1 < c) ? i1 : (c - 1), 64);
    uint4 wa = *(const uint4*)(xlp + ((unsigned)sa * (unsigned)RB + rowoff));
    uint4 wb = *(const uint4*)(xlp + ((unsigned)sb * (unsigned)RB + rowoff));

    int p = 0;
    for (; p + EL < c; p += 2 * EL){            // chain A fully live (wave-uniform)
        float mkb = (p + EL + el < c) ? 0.f : -1e30f;
        int pn = p + 2 * EL;
        uint4 wa_n, wb_n;
        bool pf = pn < c;                       // wave-uniform prefetch guard
        if (pf){                                // issue NEXT gathers before math
            int ian = pn + el, ibn = pn + EL + el;
            int sa_n = __shfl(srcAll, (ian < c) ? ian : (c - 1), 64);
            int sb_n = __shfl(srcAll, (ibn < c) ? ibn : (c - 1), 64);
            wa_n = *(const uint4*)(xlp + ((unsigned)sa_n * (unsigned)RB + rowoff));
            wb_n = *(const uint4*)(xlp + ((unsigned)sb_n * (unsigned)RB + rowoff));
        }

        f32x2 xa0 = unpk(wa.x), xa1 = unpk(wa.y), xa2 = unpk(wa.z), xa3 = unpk(wa.w);
        f32x2 xb0 = unpk(wb.x), xb1 = unpk(wb.y), xb2 = unpk(wb.z), xb3 = unpk(wb.w);

        f32x2 ua0 = xa0 + xr0, ua1 = xa1 + xr1, ua2 = xa2 + xr2v, ua3 = xa3 + xr3;
        f32x2 ub0 = xb0 + xr0, ub1 = xb1 + xr1, ub2 = xb2 + xr2v, ub3 = xb3 + xr3;

        f32x2 ppa = pkmax(ua0, ua0 * NEG_SLOPE) * av0;
        ppa += pkmax(ua1, ua1 * NEG_SLOPE) * av1;
        ppa += pkmax(ua2, ua2 * NEG_SLOPE) * av2;
        ppa += pkmax(ua3, ua3 * NEG_SLOPE) * av3;
        f32x2 ppb = pkmax(ub0, ub0 * NEG_SLOPE) * av0;
        ppb += pkmax(ub1, ub1 * NEG_SLOPE) * av1;
        ppb += pkmax(ub2, ub2 * NEG_SLOPE) * av2;
        ppb += pkmax(ub3, ub3 * NEG_SLOPE) * av3;
        float parta = group_sum<GH>(ppa.x + ppa.y);   // DPP, register-only
        float partb = group_sum<GH>(ppb.x + ppb.y);
        float exa = exp2f(parta);
        float exb = exp2f(partb + mkb);
        den += exa + exb;
        f32x2 ea = {exa, exa}, eb = {exb, exb};
        a0 += ea * xa0; a1 += ea * xa1; a2 += ea * xa2; a3 += ea * xa3;
        a0 += eb * xb0; a1 += eb * xb1; a2 += eb * xb2; a3 += eb * xb3;
        if (pf){ wa = wa_n; wb = wb_n; }
    }
    if (p < c){                                 // tail: <=EL edges, single chain
        // wa holds the prefetched gather for slot p+el (prologue or last loop iter)
        float mka = (p + el < c) ? 0.f : -1e30f;
        f32x2 xa0 = unpk(wa.x), xa1 = unpk(wa.y), xa2 = unpk(wa.z), xa3 = unpk(wa.w);
        f32x2 ua0 = xa0 + xr0, ua1 = xa1 + xr1, ua2 = xa2 + xr2v, ua3 = xa3 + xr3;

        f32x2 ppa = pkmax(ua0, ua0 * NEG_SLOPE) * av0;
        ppa += pkmax(ua1, ua1 * NEG_SLOPE) * av1;
        ppa += pkmax(ua2, ua2 * NEG_SLOPE) * av2;
        ppa += pkmax(ua3, ua3 * NEG_SLOPE) * av3;
        float parta = group_sum<GH>(ppa.x + ppa.y);
        float exa = exp2f(parta + mka);         // 0 for dead slots
        den += exa;
        f32x2 ea = {exa, exa};
        a0 += ea * xa0; a1 += ea * xa1; a2 += ea * xa2; a3 += ea * xa3;
    }

    // merge the EL edge-group partials (cold path: once per node)
    #pragma unroll
    for (int mask = LPE; mask < 64; mask <<= 1){
        den  += __shfl_xor(den, mask, 64);
        a0.x += __shfl_xor(a0.x, mask, 64); a0.y += __shfl_xor(a0.y, mask, 64);
        a1.x += __shfl_xor(a1.x, mask, 64); a1.y += __shfl_xor(a1.y, mask, 64);
        a2.x += __shfl_xor(a2.x, mask, 64); a2.y += __shfl_xor(a2.y, mask, 64);
        a3.x += __shfl_xor(a3.x, mask, 64); a3.y += __shfl_xor(a3.y, mask, 64);
    }
    float inv = 1.f / den;

    if (!MEAN){
        if (el == 0){
            uint4 o;
            o.x = pack2(a0.x * inv, a0.y * inv);
            o.y = pack2(a1.x * inv, a1.y * inv);
            o.z = pack2(a2.x * inv, a2.y * inv);
            o.w = pack2(a3.x * inv, a3.y * inv);
            *(uint4*)((char*)outv + (size_t)n * RB + rowoff) = o;
        }
    } else {
        // per-lane normalized values, then head-mean via shfl_xor(16) (h-bit)
        float v0 = a0.x * inv, v1 = a0.y * inv, v2 = a1.x * inv, v3 = a1.y * inv;
        float v4 = a2.x * inv, v5 = a2.y * inv, v6 = a3.x * inv, v7 = a3.y * inv;
        v0 = 0.5f * (v0 + __shfl_xor(v0, 16, 64)) + b2r[0];
        v1 = 0.5f * (v1 + __shfl_xor(v1, 16, 64)) + b2r[1];
        v2 = 0.5f * (v2 + __shfl_xor(v2, 16, 64)) + b2r[2];
        v3 = 0.5f * (v3 + __shfl_xor(v3, 16, 64)) + b2r[3];
        v4 = 0.5f * (v4 + __shfl_xor(v4, 16, 64)) + b2r[4];
        v5 = 0.5f * (v5 + __shfl_xor(v5, 16, 64)) + b2r[5];
        v6 = 0.5f * (v6 + __shfl_xor(v6, 16, 64)) + b2r[6];
        v7 = 0.5f * (v7 + __shfl_xor(v7, 16, 64)) + b2r[7];
        if (el == 0 && h == 0){
            float* outp = (float*)outv + (size_t)n * C + cl * 8;
            float4 w0 = {v0, v1, v2, v3};
            float4 w1 = {v4, v5, v6, v7};
            *(float4*)(outp) = w0;
            *(float4*)(outp + 4) = w1;
        }
    }
}

// ---------------- BatchNorm ----------------

// stats over packed-bf16 matrix [N][128]
__global__ void bn_stats_bf16(const unsigned int* __restrict__ x, float* __restrict__ sums){
    __shared__ float ls[1024];
    int t = threadIdx.x;              // 256 threads
    int c2 = t & 63;                  // dword column (covers ch 2*c2, 2*c2+1)
    int rg = t >> 6;                  // 4 row groups
    float s0 = 0.f, q0 = 0.f, s1 = 0.f, q1 = 0.f;
    for (int r = blockIdx.x * 4 + rg; r < NNODES; r += gridDim.x * 4){
        f32x2 v = unpk(x[(size_t)r * 64 + c2]);
        s0 += v.x; q0 += v.x * v.x;
        s1 += v.y; q1 += v.y * v.y;
    }
    ls[t] = s0; ls[256 + t] = q0; ls[512 + t] = s1; ls[768 + t] = q1;
    __syncthreads();
    if (rg == 0){
        for (int g = 1; g < 4; ++g){
            s0 += ls[g * 64 + c2];       q0 += ls[256 + g * 64 + c2];
            s1 += ls[512 + g * 64 + c2]; q1 += ls[768 + g * 64 + c2];
        }
        atomicAdd(&sums[2 * c2], s0);
        atomicAdd(&sums[128 + 2 * c2], q0);
        atomicAdd(&sums[2 * c2 + 1], s1);
        atomicAdd(&sums[128 + 2 * c2 + 1], q1);
    }
}

// stats over o2[:, 0:64] (fp32, stride 128)
__global__ void bn_stats_o2(const float* __restrict__ x, float* __restrict__ sums){
    __shared__ float ls[512];
    int t = threadIdx.x;              // 256 threads
    int col = t & 63;
    int rg  = t >> 6;                 // 4 row groups
    float s = 0.f, q = 0.f;
    for (int r = blockIdx.x * 4 + rg; r < NNODES; r += gridDim.x * 4){
        float v = x[(size_t)r * 128 + col];
        s += v; q += v * v;
    }
    ls[t] = s; ls[256 + t] = q;
    __syncthreads();
    if (rg == 0){
        for (int g = 1; g < 4; ++g){ s += ls[g * 64 + col]; q += ls[256 + g * 64 + col]; }
        atomicAdd(&sums[col], s);
        atomicAdd(&sums[64 + col], q);
    }
}

// o2 -> out: BN (affine=False, finalize inline) cols 0..63, softplus cols 64..127
// float4 per thread; 64-col boundary is 16B-aligned so a vector never straddles.
__global__ void final_out(const float* __restrict__ o2, const float* __restrict__ sums,
                          float* __restrict__ out){
    int i = blockIdx.x * blockDim.x + threadIdx.x;
    if (i >= NNODES * 32) return;
    float4 v = *(const float4*)(o2 + (size_t)i * 4);
    int c = (i * 4) & 127;
    const float* vp = (const float*)&v;
    float4 r;
    float* rp = (float*)&r;
    if (c < 64){
        const float inv_n = 1.f / (float)NNODES;
        #pragma unroll
        for (int k = 0; k < 4; ++k){
            float mu = sums[c + k] * inv_n;
            float rsig = rsqrtf(sums[64 + c + k] * inv_n - mu * mu + BN_EPS);
            rp[k] = (vp[k] - mu) * rsig;
        }
    } else {
        #pragma unroll
        for (int k = 0; k < 4; ++k){
            float x = vp[k];
            rp[k] = (x > 20.f) ? x : log1pf(__expf(x)); // softplus (incl bias2)
        }
    }
    *(float4*)(out + (size_t)i * 4) = r;
}

// ---------------- launch ----------------

extern "C" void kernel_launch(void* const* d_in, const int* in_sizes, int n_in,
                              void* d_out, int out_size, void* d_ws, size_t ws_size,
                              hipStream_t stream) {
    const float* x     = (const float*)d_in[0];
    const int*   ei    = (const int*)d_in[1];
    const float* W_l1  = (const float*)d_in[2];
    const float* b_l1  = (const float*)d_in[3];
    const float* W_r1  = (const float*)d_in[4];
    const float* b_r1  = (const float*)d_in[5];
    const float* att1  = (const float*)d_in[6];
    // d_in[7] = bias1: cancels through BN1 (constant per-column shift) -> unused
    const float* gamma1 = (const float*)d_in[8];
    const float* beta1  = (const float*)d_in[9];
    const float* W_l2  = (const float*)d_in[10];
    const float* b_l2  = (const float*)d_in[11];
    const float* W_r2  = (const float*)d_in[12];
    const float* b_r2  = (const float*)d_in[13];
    const float* att2  = (const float*)d_in[14];
    const float* bias2 = (const float*)d_in[15];
    float* out = (float*)d_out;

    char* w = (char*)d_ws;
    size_t off = 0;
    auto alloc = [&](size_t bytes) -> void* {
        void* p = w + off;
        off += (bytes + 255) & ~(size_t)255;
        return p;
    };
    const size_t NF  = (size_t)NNODES * 128 * 4;   // 25.6 MB fp32
    bf16*  xl1   = (bf16*) alloc(NF / 2);          // N x 128 bf16
    bf16*  xr1   = (bf16*) alloc(NF / 2);
    bf16*  xl2   = (bf16*) alloc(NF);              // N x 256 bf16
    bf16*  xr2   = (bf16*) alloc(NF);
    unsigned int* o1 = (unsigned int*)alloc(NF / 2);  // N x 128 bf16 (packed)
    float* o2    = (float*)alloc(NF);              // N x 128 fp32
    bf16*  WT1   = (bf16*) alloc(256 * 128 * 2);
    bf16*  WT2   = (bf16*) alloc(512 * 128 * 2);
    float* bc1   = (float*)alloc(256 * 4);
    float* bc2   = (float*)alloc(512 * 4);
    int*   cnt    = (int*)  alloc((size_t)NNODES * 4);
    unsigned short* esrc = (unsigned short*)alloc((size_t)NNODES * ESLOT * 2); // 6.4 MB
    float* bnsums = (float*)alloc(384 * 4);   // bn1: 256 (sum|sq), bn2: 128 (sum|sq)
    float* bn1s = bnsums;
    float* bn2s = bnsums + 256;

    // weight transposes + cnt/bnsums zero-fill (replaces 2 memset dispatches)
    misc_prep<<<PB_W2 + PB_Z, 256, 0, stream>>>(W_l1, W_r1, b_l1, b_r1, WT1, bc1,
                                                W_l2, W_r2, b_l2, b_r2, WT2, bc2,
                                                cnt, bnsums);

    // conv1 gemm (A = fp32 x) + edge scatter hidden in extra blocks
    mfma_gemm<128, 1, 2, true><<<dim3(GEMM1_GX + SCAT_NB, 2), 128, 0, stream>>>(
        x, WT1, bc1, xl1, xr1, nullptr, nullptr, nullptr, ei, cnt, esrc);
    gat_aggregate<64, false><<<NNODES / 4, 256, 0, stream>>>(
        xl1, xr1, att1, cnt, esrc, o1, bias2);

    // bn1 stats; BN+ReLU applied inline in gemm2's A-fragment loader
    bn_stats_bf16<<<512, 256, 0, stream>>>(o1, bn1s);

    // conv2 -> xl2/xr2; A = o1 with inline BN1+ReLU
    mfma_gemm<256, 2, 2, false><<<dim3(392, 4), 128, 0, stream>>>(
        o1, WT2, bc2, xl2, xr2, bn1s, gamma1, beta1, nullptr, nullptr, nullptr);
    gat_aggregate<128, true><<<NNODES / 4, 256, 0, stream>>>(
        xl2, xr2, att2, cnt, esrc, o2, bias2);

    // bn2 stats on o2 cols 0..63, then fused BN+softplus -> out
    bn_stats_o2<<<512, 256, 0, stream>>>(o2, bn2s);
    final_out<<<(NNODES * 32 + 255) / 256, 256, 0, stream>>>(o2, bn2s, out);
}